// Round 7
// baseline (358.288 us; speedup 1.0000x reference)
//
#include <hip/hip_runtime.h>
#include <hip/hip_bf16.h>

#define D 64
#define WAVE 64
#define SCAN_B 1024
#define NB 8

// ------------- K1: transform (blocks [0,tblocks)) + dst histogram ----------
// Transform: W columns live in VGPRs (wl[64]/wr[64], statically indexed by
// full unroll). x row values are wave-uniform -> readfirstlane'd base makes
// the compiler emit scalar (SMEM) loads. Inner loop = pure v_fma. No LDS.
__global__ __launch_bounds__(256) void transform_hist_kernel(
    const float* __restrict__ x, const float* __restrict__ Wl,
    const float* __restrict__ bl, const float* __restrict__ Wr,
    const float* __restrict__ br, __hip_bfloat16* __restrict__ xlb,
    float* __restrict__ xr, const int* __restrict__ ei,
    int* __restrict__ cnt, int n, int E_, int tblocks) {
    if ((int)blockIdx.x < tblocks) {
        const int lane = threadIdx.x & (WAVE - 1);
        float wl[D], wr[D];
#pragma unroll
        for (int k = 0; k < D; ++k) {
            wl[k] = Wl[k * D + lane];   // coalesced 256B per k
            wr[k] = Wr[k * D + lane];
        }
        const float bll = bl[lane];
        const float brl = br[lane];
        const int wid = (blockIdx.x * blockDim.x + threadIdx.x) >> 6;
        const int nw = (tblocks * blockDim.x) >> 6;
        const int ngrp = (n + NB - 1) / NB;
        for (int g = wid; g < ngrp; g += nw) {
            const int node0 = __builtin_amdgcn_readfirstlane(g * NB);
            const float* __restrict__ xb = x + (size_t)node0 * D;
            float accl[NB], accr[NB];
#pragma unroll
            for (int t = 0; t < NB; ++t) { accl[t] = bll; accr[t] = brl; }
            if (node0 + NB <= n) {
#pragma unroll
                for (int kc = 0; kc < D; kc += 4) {
                    float xs[NB][4];
#pragma unroll
                    for (int t = 0; t < NB; ++t)
#pragma unroll
                        for (int j = 0; j < 4; ++j)
                            xs[t][j] = xb[t * D + kc + j];  // uniform -> s_load
#pragma unroll
                    for (int j = 0; j < 4; ++j)
#pragma unroll
                        for (int t = 0; t < NB; ++t) {
                            accl[t] = fmaf(xs[t][j], wl[kc + j], accl[t]);
                            accr[t] = fmaf(xs[t][j], wr[kc + j], accr[t]);
                        }
                }
#pragma unroll
                for (int t = 0; t < NB; ++t) {
                    const size_t off = (size_t)(node0 + t) * D + lane;
                    xlb[off] = __float2bfloat16(accl[t]);
                    xr[off] = accr[t];
                }
            } else {
                for (int t = 0; t < NB && node0 + t < n; ++t) {
                    float al = bll, ar = brl;
#pragma unroll
                    for (int k = 0; k < D; ++k) {
                        const float xv = xb[t * D + k];
                        al = fmaf(xv, wl[k], al);
                        ar = fmaf(xv, wr[k], ar);
                    }
                    const size_t off = (size_t)(node0 + t) * D + lane;
                    xlb[off] = __float2bfloat16(al);
                    xr[off] = ar;
                }
            }
        }
    } else {
        const int tid = (blockIdx.x - tblocks) * blockDim.x + threadIdx.x;
        const int stride = (gridDim.x - tblocks) * blockDim.x;
        for (int j = tid; j < E_; j += stride)
            atomicAdd(&cnt[ei[E_ + j]], 1);
    }
}

// ------------- scan: per-block exclusive scan + block sums -----------------
__global__ void scan_local(const int* __restrict__ cnt, int* __restrict__ cursor,
                           int* __restrict__ bsums, int n) {
    __shared__ int tmp[SCAN_B];
    const int t = threadIdx.x;
    const int gid = blockIdx.x * SCAN_B + t;
    const int v = (gid < n) ? cnt[gid] : 0;
    tmp[t] = v;
    __syncthreads();
    for (int off = 1; off < SCAN_B; off <<= 1) {
        int u = (t >= off) ? tmp[t - off] : 0;
        __syncthreads();
        tmp[t] += u;
        __syncthreads();
    }
    if (gid < n) cursor[gid] = tmp[t] - v;  // block-local exclusive start
    if (t == SCAN_B - 1) bsums[blockIdx.x] = tmp[t];
}

__global__ void scan_tops(int* __restrict__ bsums, int nb) {
    __shared__ int tmp[SCAN_B];
    const int t = threadIdx.x;
    const int v = (t < nb) ? bsums[t] : 0;
    tmp[t] = v;
    __syncthreads();
    for (int off = 1; off < SCAN_B; off <<= 1) {
        int u = (t >= off) ? tmp[t - off] : 0;
        __syncthreads();
        tmp[t] += u;
        __syncthreads();
    }
    if (t < nb) bsums[t] = tmp[t] - v;  // exclusive block bases
}

// ------------- gather-fill CSR: one WG per 1024-node dst slab --------------
// Streams the whole dst array (int4), appends matching srcs into the WG's
// CONTIGUOUS esrc region using LDS cursors. No global atomics, no scattered
// partial-line HBM writes. cursor[] is read-only here.
__global__ __launch_bounds__(1024) void fill_gather_kernel(
    const int* __restrict__ ei, const int* __restrict__ cursor,
    const int* __restrict__ bsums, int* __restrict__ esrc, int E_, int n) {
    __shared__ int lcur[SCAN_B];
    const int base = blockIdx.x * SCAN_B;
    const int gbase = bsums[blockIdx.x];
    for (int i = threadIdx.x; i < SCAN_B; i += blockDim.x) {
        const int gid = base + i;
        lcur[i] = (gid < n) ? (gbase + cursor[gid]) : 0;
    }
    __syncthreads();
    const int hi = min(base + SCAN_B, n);
    const int* __restrict__ dstp = ei + E_;
    const int nvec = E_ >> 2;
    for (int q = threadIdx.x; q < nvec; q += blockDim.x) {
        const int j = q << 2;
        const int4 d4 = *reinterpret_cast<const int4*>(dstp + j);
        if (d4.x >= base && d4.x < hi) {
            const int p = atomicAdd(&lcur[d4.x - base], 1);
            esrc[p] = ei[j];
        }
        if (d4.y >= base && d4.y < hi) {
            const int p = atomicAdd(&lcur[d4.y - base], 1);
            esrc[p] = ei[j + 1];
        }
        if (d4.z >= base && d4.z < hi) {
            const int p = atomicAdd(&lcur[d4.z - base], 1);
            esrc[p] = ei[j + 2];
        }
        if (d4.w >= base && d4.w < hi) {
            const int p = atomicAdd(&lcur[d4.w - base], 1);
            esrc[p] = ei[j + 3];
        }
    }
    for (int j = (nvec << 2) + threadIdx.x; j < E_; j += blockDim.x) {
        const int d = dstp[j];
        if (d >= base && d < hi) {
            const int p = atomicAdd(&lcur[d - base], 1);
            esrc[p] = ei[j];
        }
    }
}

// ------------- fused: softmax-attention aggregate + bias + LN --------------
__global__ __launch_bounds__(256) void fused_kernel(
    const int* __restrict__ esrc, const int* __restrict__ cursor,
    const int* __restrict__ bsums, const int* __restrict__ cnt,
    const __hip_bfloat16* __restrict__ xlb, const float* __restrict__ xr,
    const float* __restrict__ att, const float* __restrict__ bias,
    const float* __restrict__ gamma, const float* __restrict__ beta,
    float* __restrict__ out, int n) {
    const int lane = threadIdx.x & (WAVE - 1);
    const int sub = lane & 15;   // dim slice
    const int grp = lane >> 4;   // edge group 0..3
    const int wid = (blockIdx.x * blockDim.x + threadIdx.x) >> 6;
    const int nw = (gridDim.x * blockDim.x) >> 6;

    const float4 a4 = reinterpret_cast<const float4*>(att)[sub];
    const float4 b4 = reinterpret_cast<const float4*>(bias)[sub];
    const float4 g4 = reinterpret_cast<const float4*>(gamma)[sub];
    const float4 be4 = reinterpret_cast<const float4*>(beta)[sub];

    for (int node = wid; node < n; node += nw) {
        const float4 xr4 = reinterpret_cast<const float4*>(xr + (size_t)node * D)[sub];
        const int c = cnt[node];
        const int beg = bsums[node >> 10] + cursor[node];  // cursor = row start
        const int total = c + 1;  // + self loop

        float zacc = 0.f;
        float acc0 = 0.f, acc1 = 0.f, acc2 = 0.f, acc3 = 0.f;

        for (int base = 0; base < total; base += WAVE) {
            const int cc = min(WAVE, total - base);
            const int gidx = base + lane;
            const int myi = (gidx < c) ? esrc[beg + gidx] : node;

            for (int k = 0; k < cc; k += 8) {
                const int idxA = k + grp;
                const int idxB = k + 4 + grp;
                const bool vA = idxA < cc;
                const bool vB = idxB < cc;
                const int sA = __shfl(myi, vA ? idxA : 0, WAVE);
                const int sB = __shfl(myi, vB ? idxB : 0, WAVE);
                const uint2 rA = *reinterpret_cast<const uint2*>(
                    xlb + (size_t)sA * D + 4 * sub);
                const uint2 rB = *reinterpret_cast<const uint2*>(
                    xlb + (size_t)sB * D + 4 * sub);

                // ---- edge A ----
                {
                    const float x0 = __uint_as_float(rA.x << 16);
                    const float x1 = __uint_as_float(rA.x & 0xffff0000u);
                    const float x2 = __uint_as_float(rA.y << 16);
                    const float x3 = __uint_as_float(rA.y & 0xffff0000u);
                    float v0 = x0 + xr4.x; v0 = (v0 > 0.f) ? v0 : 0.2f * v0;
                    float v1 = x1 + xr4.y; v1 = (v1 > 0.f) ? v1 : 0.2f * v1;
                    float v2 = x2 + xr4.z; v2 = (v2 > 0.f) ? v2 : 0.2f * v2;
                    float v3 = x3 + xr4.w; v3 = (v3 > 0.f) ? v3 : 0.2f * v3;
                    float t = v0 * a4.x;
                    t = fmaf(v1, a4.y, t);
                    t = fmaf(v2, a4.z, t);
                    t = fmaf(v3, a4.w, t);
#pragma unroll
                    for (int off = 1; off < 16; off <<= 1)
                        t += __shfl_xor(t, off, WAVE);
                    const float p = vA ? __expf(t) : 0.f;
                    zacc += p;
                    acc0 = fmaf(p, x0, acc0);
                    acc1 = fmaf(p, x1, acc1);
                    acc2 = fmaf(p, x2, acc2);
                    acc3 = fmaf(p, x3, acc3);
                }
                // ---- edge B ----
                {
                    const float x0 = __uint_as_float(rB.x << 16);
                    const float x1 = __uint_as_float(rB.x & 0xffff0000u);
                    const float x2 = __uint_as_float(rB.y << 16);
                    const float x3 = __uint_as_float(rB.y & 0xffff0000u);
                    float v0 = x0 + xr4.x; v0 = (v0 > 0.f) ? v0 : 0.2f * v0;
                    float v1 = x1 + xr4.y; v1 = (v1 > 0.f) ? v1 : 0.2f * v1;
                    float v2 = x2 + xr4.z; v2 = (v2 > 0.f) ? v2 : 0.2f * v2;
                    float v3 = x3 + xr4.w; v3 = (v3 > 0.f) ? v3 : 0.2f * v3;
                    float t = v0 * a4.x;
                    t = fmaf(v1, a4.y, t);
                    t = fmaf(v2, a4.z, t);
                    t = fmaf(v3, a4.w, t);
#pragma unroll
                    for (int off = 1; off < 16; off <<= 1)
                        t += __shfl_xor(t, off, WAVE);
                    const float p = vB ? __expf(t) : 0.f;
                    zacc += p;
                    acc0 = fmaf(p, x0, acc0);
                    acc1 = fmaf(p, x1, acc1);
                    acc2 = fmaf(p, x2, acc2);
                    acc3 = fmaf(p, x3, acc3);
                }
            }
        }
        // cross-group combine
#pragma unroll
        for (int off = 16; off < 64; off <<= 1) {
            zacc += __shfl_xor(zacc, off, WAVE);
            acc0 += __shfl_xor(acc0, off, WAVE);
            acc1 += __shfl_xor(acc1, off, WAVE);
            acc2 += __shfl_xor(acc2, off, WAVE);
            acc3 += __shfl_xor(acc3, off, WAVE);
        }
        const float inv = 1.f / zacc;
        const float o0 = fmaf(acc0, inv, b4.x);
        const float o1 = fmaf(acc1, inv, b4.y);
        const float o2 = fmaf(acc2, inv, b4.z);
        const float o3 = fmaf(acc3, inv, b4.w);
        float s1 = (o0 + o1) + (o2 + o3);
#pragma unroll
        for (int off = 1; off < 16; off <<= 1) s1 += __shfl_xor(s1, off, WAVE);
        const float mu = s1 * (1.0f / D);
        const float d0 = o0 - mu, d1 = o1 - mu, d2 = o2 - mu, d3 = o3 - mu;
        float s2 = (d0 * d0 + d1 * d1) + (d2 * d2 + d3 * d3);
#pragma unroll
        for (int off = 1; off < 16; off <<= 1) s2 += __shfl_xor(s2, off, WAVE);
        const float rs = rsqrtf(s2 * (1.0f / D) + 1e-5f);
        if (grp == 0) {
            float4 r;
            r.x = d0 * rs * g4.x + be4.x;
            r.y = d1 * rs * g4.y + be4.y;
            r.z = d2 * rs * g4.z + be4.z;
            r.w = d3 * rs * g4.w + be4.w;
            reinterpret_cast<float4*>(out + (size_t)node * D)[sub] = r;
        }
    }
}

extern "C" void kernel_launch(void* const* d_in, const int* in_sizes, int n_in,
                              void* d_out, int out_size, void* d_ws, size_t ws_size,
                              hipStream_t stream) {
    const float* x = (const float*)d_in[0];
    const int* ei = (const int*)d_in[1];
    const float* Wl = (const float*)d_in[2];
    const float* bl = (const float*)d_in[3];
    const float* Wr = (const float*)d_in[4];
    const float* br = (const float*)d_in[5];
    const float* att = (const float*)d_in[6];
    const float* bias = (const float*)d_in[7];
    const float* gamma = (const float*)d_in[8];
    const float* beta = (const float*)d_in[9];

    const int n = in_sizes[0] / D;   // 100000
    const int E_ = in_sizes[1] / 2;  // 1000000
    const int nb = (n + SCAN_B - 1) / SCAN_B;

    char* ws = (char*)d_ws;
    __hip_bfloat16* xlb = (__hip_bfloat16*)ws;                       // n*D bf16
    float* xr = (float*)(ws + (((size_t)n * D * 2 + 255) & ~255ul)); // n*D f32
    int* cnt = (int*)((char*)xr + (size_t)n * D * 4);                // n
    int* cursor = cnt + n;                                           // n
    int* bsums = cursor + n;                                         // nb
    int* esrc = bsums + ((nb + 63) & ~63);                           // E_

    hipMemsetAsync(cnt, 0, (size_t)n * sizeof(int), stream);

    transform_hist_kernel<<<2048, 256, 0, stream>>>(x, Wl, bl, Wr, br, xlb, xr,
                                                    ei, cnt, n, E_, 1024);
    scan_local<<<nb, SCAN_B, 0, stream>>>(cnt, cursor, bsums, n);
    scan_tops<<<1, SCAN_B, 0, stream>>>(bsums, nb);
    fill_gather_kernel<<<nb, 1024, 0, stream>>>(ei, cursor, bsums, esrc, E_, n);
    fused_kernel<<<2048, 256, 0, stream>>>(esrc, cursor, bsums, cnt, xlb, xr,
                                           att, bias, gamma, beta,
                                           (float*)d_out, n);
}

// Round 8
// 195.123 us; speedup vs baseline: 1.8362x; 1.8362x over previous
//
#include <hip/hip_runtime.h>
#include <hip/hip_bf16.h>

#define D 64
#define WAVE 64
#define SCAN_B 1024
#define NB 8

// ------------- K1: transform (blocks [0,tblocks)) + dst histogram ----------
// Transform: W columns live in VGPRs (wl[64]/wr[64], statically indexed by
// full unroll). x row values are wave-uniform -> readfirstlane'd base makes
// the compiler emit scalar (SMEM) loads. Inner loop = pure v_fma. No LDS.
// Hist: XCD-partitioned — WG class (bid&7) only counts dsts whose slab class
// ((d>>10)&7) matches, so cnt cache lines stay on one XCD's L2 (heuristic:
// blockIdx%8 ~ XCD id; correctness does not depend on it).
__global__ __launch_bounds__(256) void transform_hist_kernel(
    const float* __restrict__ x, const float* __restrict__ Wl,
    const float* __restrict__ bl, const float* __restrict__ Wr,
    const float* __restrict__ br, __hip_bfloat16* __restrict__ xlb,
    float* __restrict__ xr, const int* __restrict__ ei,
    int* __restrict__ cnt, int n, int E_, int tblocks) {
    if ((int)blockIdx.x < tblocks) {
        const int lane = threadIdx.x & (WAVE - 1);
        float wl[D], wr[D];
#pragma unroll
        for (int k = 0; k < D; ++k) {
            wl[k] = Wl[k * D + lane];   // coalesced 256B per k
            wr[k] = Wr[k * D + lane];
        }
        const float bll = bl[lane];
        const float brl = br[lane];
        const int wid = (blockIdx.x * blockDim.x + threadIdx.x) >> 6;
        const int nw = (tblocks * blockDim.x) >> 6;
        const int ngrp = (n + NB - 1) / NB;
        for (int g = wid; g < ngrp; g += nw) {
            const int node0 = __builtin_amdgcn_readfirstlane(g * NB);
            const float* __restrict__ xb = x + (size_t)node0 * D;
            float accl[NB], accr[NB];
#pragma unroll
            for (int t = 0; t < NB; ++t) { accl[t] = bll; accr[t] = brl; }
            if (node0 + NB <= n) {
#pragma unroll
                for (int kc = 0; kc < D; kc += 4) {
                    float xs[NB][4];
#pragma unroll
                    for (int t = 0; t < NB; ++t)
#pragma unroll
                        for (int j = 0; j < 4; ++j)
                            xs[t][j] = xb[t * D + kc + j];  // uniform -> s_load
#pragma unroll
                    for (int j = 0; j < 4; ++j)
#pragma unroll
                        for (int t = 0; t < NB; ++t) {
                            accl[t] = fmaf(xs[t][j], wl[kc + j], accl[t]);
                            accr[t] = fmaf(xs[t][j], wr[kc + j], accr[t]);
                        }
                }
#pragma unroll
                for (int t = 0; t < NB; ++t) {
                    const size_t off = (size_t)(node0 + t) * D + lane;
                    xlb[off] = __float2bfloat16(accl[t]);
                    xr[off] = accr[t];
                }
            } else {
                for (int t = 0; t < NB && node0 + t < n; ++t) {
                    float al = bll, ar = brl;
#pragma unroll
                    for (int k = 0; k < D; ++k) {
                        const float xv = xb[t * D + k];
                        al = fmaf(xv, wl[k], al);
                        ar = fmaf(xv, wr[k], ar);
                    }
                    const size_t off = (size_t)(node0 + t) * D + lane;
                    xlb[off] = __float2bfloat16(al);
                    xr[off] = ar;
                }
            }
        }
    } else {
        const int hbid = blockIdx.x - tblocks;
        const int xcd = hbid & 7;
        const int chunk = hbid >> 3;
        const int nchunks = (gridDim.x - tblocks) >> 3;
        const int lo = (int)((long long)E_ * chunk / nchunks);
        const int hi = (int)((long long)E_ * (chunk + 1) / nchunks);
        for (int j = lo + (int)threadIdx.x; j < hi; j += blockDim.x) {
            const int d = ei[E_ + j];
            if (((d >> 10) & 7) == xcd) atomicAdd(&cnt[d], 1);
        }
    }
}

// ------------- scan: per-block exclusive scan + block sums -----------------
__global__ void scan_local(const int* __restrict__ cnt, int* __restrict__ cursor,
                           int* __restrict__ bsums, int n) {
    __shared__ int tmp[SCAN_B];
    const int t = threadIdx.x;
    const int gid = blockIdx.x * SCAN_B + t;
    const int v = (gid < n) ? cnt[gid] : 0;
    tmp[t] = v;
    __syncthreads();
    for (int off = 1; off < SCAN_B; off <<= 1) {
        int u = (t >= off) ? tmp[t - off] : 0;
        __syncthreads();
        tmp[t] += u;
        __syncthreads();
    }
    if (gid < n) cursor[gid] = tmp[t] - v;  // block-local exclusive start
    if (t == SCAN_B - 1) bsums[blockIdx.x] = tmp[t];
}

__global__ void scan_tops(int* __restrict__ bsums, int nb) {
    __shared__ int tmp[SCAN_B];
    const int t = threadIdx.x;
    const int v = (t < nb) ? bsums[t] : 0;
    tmp[t] = v;
    __syncthreads();
    for (int off = 1; off < SCAN_B; off <<= 1) {
        int u = (t >= off) ? tmp[t - off] : 0;
        __syncthreads();
        tmp[t] += u;
        __syncthreads();
    }
    if (t < nb) bsums[t] = tmp[t] - v;  // exclusive block bases
}

// ------------- fill CSR: XCD-partitioned scatter ---------------------------
// WG class (bid&7) handles only dst slabs of the same class; each edge chunk
// is scanned by all 8 classes (reads served by L2/L3), so every esrc/cursor
// cache line is written from one XCD only -> lines fill before eviction.
__global__ __launch_bounds__(256) void fill_kernel(
    const int* __restrict__ ei, int* __restrict__ cursor,
    const int* __restrict__ bsums, int* __restrict__ esrc, int E_) {
    const int xcd = blockIdx.x & 7;
    const int chunk = blockIdx.x >> 3;
    const int nchunks = gridDim.x >> 3;
    const int lo = (int)((long long)E_ * chunk / nchunks);
    const int hi = (int)((long long)E_ * (chunk + 1) / nchunks);
    for (int j = lo + (int)threadIdx.x; j < hi; j += blockDim.x) {
        const int d = ei[E_ + j];
        if (((d >> 10) & 7) == xcd) {
            const int pos = bsums[d >> 10] + atomicAdd(&cursor[d], 1);
            esrc[pos] = ei[j];
        }
    }
}

// ------------- fused: softmax-attention aggregate + bias + LN --------------
__global__ __launch_bounds__(256) void fused_kernel(
    const int* __restrict__ esrc, const int* __restrict__ cursor,
    const int* __restrict__ bsums, const int* __restrict__ cnt,
    const __hip_bfloat16* __restrict__ xlb, const float* __restrict__ xr,
    const float* __restrict__ att, const float* __restrict__ bias,
    const float* __restrict__ gamma, const float* __restrict__ beta,
    float* __restrict__ out, int n) {
    const int lane = threadIdx.x & (WAVE - 1);
    const int sub = lane & 15;   // dim slice
    const int grp = lane >> 4;   // edge group 0..3
    const int wid = (blockIdx.x * blockDim.x + threadIdx.x) >> 6;
    const int nw = (gridDim.x * blockDim.x) >> 6;

    const float4 a4 = reinterpret_cast<const float4*>(att)[sub];
    const float4 b4 = reinterpret_cast<const float4*>(bias)[sub];
    const float4 g4 = reinterpret_cast<const float4*>(gamma)[sub];
    const float4 be4 = reinterpret_cast<const float4*>(beta)[sub];

    for (int node = wid; node < n; node += nw) {
        const float4 xr4 = reinterpret_cast<const float4*>(xr + (size_t)node * D)[sub];
        const int c = cnt[node];
        // fill advanced cursor by c: row start = bsums + cursor - c
        const int beg = bsums[node >> 10] + cursor[node] - c;
        const int total = c + 1;  // + self loop

        float zacc = 0.f;
        float acc0 = 0.f, acc1 = 0.f, acc2 = 0.f, acc3 = 0.f;

        for (int base = 0; base < total; base += WAVE) {
            const int cc = min(WAVE, total - base);
            const int gidx = base + lane;
            const int myi = (gidx < c) ? esrc[beg + gidx] : node;

            for (int k = 0; k < cc; k += 8) {
                const int idxA = k + grp;
                const int idxB = k + 4 + grp;
                const bool vA = idxA < cc;
                const bool vB = idxB < cc;
                const int sA = __shfl(myi, vA ? idxA : 0, WAVE);
                const int sB = __shfl(myi, vB ? idxB : 0, WAVE);
                const uint2 rA = *reinterpret_cast<const uint2*>(
                    xlb + (size_t)sA * D + 4 * sub);
                const uint2 rB = *reinterpret_cast<const uint2*>(
                    xlb + (size_t)sB * D + 4 * sub);

                // ---- edge A ----
                {
                    const float x0 = __uint_as_float(rA.x << 16);
                    const float x1 = __uint_as_float(rA.x & 0xffff0000u);
                    const float x2 = __uint_as_float(rA.y << 16);
                    const float x3 = __uint_as_float(rA.y & 0xffff0000u);
                    float v0 = x0 + xr4.x; v0 = (v0 > 0.f) ? v0 : 0.2f * v0;
                    float v1 = x1 + xr4.y; v1 = (v1 > 0.f) ? v1 : 0.2f * v1;
                    float v2 = x2 + xr4.z; v2 = (v2 > 0.f) ? v2 : 0.2f * v2;
                    float v3 = x3 + xr4.w; v3 = (v3 > 0.f) ? v3 : 0.2f * v3;
                    float t = v0 * a4.x;
                    t = fmaf(v1, a4.y, t);
                    t = fmaf(v2, a4.z, t);
                    t = fmaf(v3, a4.w, t);
#pragma unroll
                    for (int off = 1; off < 16; off <<= 1)
                        t += __shfl_xor(t, off, WAVE);
                    const float p = vA ? __expf(t) : 0.f;
                    zacc += p;
                    acc0 = fmaf(p, x0, acc0);
                    acc1 = fmaf(p, x1, acc1);
                    acc2 = fmaf(p, x2, acc2);
                    acc3 = fmaf(p, x3, acc3);
                }
                // ---- edge B ----
                {
                    const float x0 = __uint_as_float(rB.x << 16);
                    const float x1 = __uint_as_float(rB.x & 0xffff0000u);
                    const float x2 = __uint_as_float(rB.y << 16);
                    const float x3 = __uint_as_float(rB.y & 0xffff0000u);
                    float v0 = x0 + xr4.x; v0 = (v0 > 0.f) ? v0 : 0.2f * v0;
                    float v1 = x1 + xr4.y; v1 = (v1 > 0.f) ? v1 : 0.2f * v1;
                    float v2 = x2 + xr4.z; v2 = (v2 > 0.f) ? v2 : 0.2f * v2;
                    float v3 = x3 + xr4.w; v3 = (v3 > 0.f) ? v3 : 0.2f * v3;
                    float t = v0 * a4.x;
                    t = fmaf(v1, a4.y, t);
                    t = fmaf(v2, a4.z, t);
                    t = fmaf(v3, a4.w, t);
#pragma unroll
                    for (int off = 1; off < 16; off <<= 1)
                        t += __shfl_xor(t, off, WAVE);
                    const float p = vB ? __expf(t) : 0.f;
                    zacc += p;
                    acc0 = fmaf(p, x0, acc0);
                    acc1 = fmaf(p, x1, acc1);
                    acc2 = fmaf(p, x2, acc2);
                    acc3 = fmaf(p, x3, acc3);
                }
            }
        }
        // cross-group combine
#pragma unroll
        for (int off = 16; off < 64; off <<= 1) {
            zacc += __shfl_xor(zacc, off, WAVE);
            acc0 += __shfl_xor(acc0, off, WAVE);
            acc1 += __shfl_xor(acc1, off, WAVE);
            acc2 += __shfl_xor(acc2, off, WAVE);
            acc3 += __shfl_xor(acc3, off, WAVE);
        }
        const float inv = 1.f / zacc;
        const float o0 = fmaf(acc0, inv, b4.x);
        const float o1 = fmaf(acc1, inv, b4.y);
        const float o2 = fmaf(acc2, inv, b4.z);
        const float o3 = fmaf(acc3, inv, b4.w);
        float s1 = (o0 + o1) + (o2 + o3);
#pragma unroll
        for (int off = 1; off < 16; off <<= 1) s1 += __shfl_xor(s1, off, WAVE);
        const float mu = s1 * (1.0f / D);
        const float d0 = o0 - mu, d1 = o1 - mu, d2 = o2 - mu, d3 = o3 - mu;
        float s2 = (d0 * d0 + d1 * d1) + (d2 * d2 + d3 * d3);
#pragma unroll
        for (int off = 1; off < 16; off <<= 1) s2 += __shfl_xor(s2, off, WAVE);
        const float rs = rsqrtf(s2 * (1.0f / D) + 1e-5f);
        if (grp == 0) {
            float4 r;
            r.x = d0 * rs * g4.x + be4.x;
            r.y = d1 * rs * g4.y + be4.y;
            r.z = d2 * rs * g4.z + be4.z;
            r.w = d3 * rs * g4.w + be4.w;
            reinterpret_cast<float4*>(out + (size_t)node * D)[sub] = r;
        }
    }
}

extern "C" void kernel_launch(void* const* d_in, const int* in_sizes, int n_in,
                              void* d_out, int out_size, void* d_ws, size_t ws_size,
                              hipStream_t stream) {
    const float* x = (const float*)d_in[0];
    const int* ei = (const int*)d_in[1];
    const float* Wl = (const float*)d_in[2];
    const float* bl = (const float*)d_in[3];
    const float* Wr = (const float*)d_in[4];
    const float* br = (const float*)d_in[5];
    const float* att = (const float*)d_in[6];
    const float* bias = (const float*)d_in[7];
    const float* gamma = (const float*)d_in[8];
    const float* beta = (const float*)d_in[9];

    const int n = in_sizes[0] / D;   // 100000
    const int E_ = in_sizes[1] / 2;  // 1000000
    const int nb = (n + SCAN_B - 1) / SCAN_B;

    char* ws = (char*)d_ws;
    __hip_bfloat16* xlb = (__hip_bfloat16*)ws;                       // n*D bf16
    float* xr = (float*)(ws + (((size_t)n * D * 2 + 255) & ~255ul)); // n*D f32
    int* cnt = (int*)((char*)xr + (size_t)n * D * 4);                // n
    int* cursor = cnt + n;                                           // n
    int* bsums = cursor + n;                                         // nb
    int* esrc = bsums + ((nb + 63) & ~63);                           // E_

    hipMemsetAsync(cnt, 0, (size_t)n * sizeof(int), stream);

    transform_hist_kernel<<<2048, 256, 0, stream>>>(x, Wl, bl, Wr, br, xlb, xr,
                                                    ei, cnt, n, E_, 1024);
    scan_local<<<nb, SCAN_B, 0, stream>>>(cnt, cursor, bsums, n);
    scan_tops<<<1, SCAN_B, 0, stream>>>(bsums, nb);
    fill_kernel<<<2048, 256, 0, stream>>>(ei, cursor, bsums, esrc, E_);
    fused_kernel<<<2048, 256, 0, stream>>>(esrc, cursor, bsums, cnt, xlb, xr,
                                           att, bias, gamma, beta,
                                           (float*)d_out, n);
}